// Round 4
// baseline (470.574 us; speedup 1.0000x reference)
//
#include <hip/hip_runtime.h>

// Involution2d fused, MFMA + sliding-window involution.
// Block = (batch, 8-row x 16-col tile), 256 threads / 4 waves, 2 blocks/CU.
// Phase 1: rT[p][o] = bf16(ReLU(BN(w_reduce @ x)))   via mfma 16x16x32 bf16
// Phase 2 per group: kernel-gen MFMA -> s_w[k][p] fp32; involution.
// R2: lgkm-only barriers + register-staged prefetch (2x win, latency-bound fix).
// R3: LDS is now the saturated pipe (8.0K cyc/CU/group ~= ideal bank BW).
//     Cut LDS read volume: wave-specialized involution - waves 0,1 do the
//     involution with 4 px x 4 planes per lane (halves s_w read volume:
//     4x49 -> 2x49 b128 per block-group); waves 2,3 own phase-2 staging
//     (regs -> LDS writes -> prefetch issue) and idle through involution.

typedef __attribute__((ext_vector_type(8))) short bf16x8;
typedef __attribute__((ext_vector_type(4))) float f32x4;

namespace {
constexpr int Cn = 256, Hn = 64, Wn = 64, HWn = 4096;
constexpr int Gn = 16, CGn = 16, CRn = 64;
constexpr int Kn = 7, PADn = 3, KKn = 49;
constexpr int TH = 8, TW = 16, TP = 128;   // tile pixels
constexpr int LD = 72, LDW = 36;           // bf16 row stride (64 + 8 pad) / dwords
constexpr int WLD = 132;                   // s_w fp32 row stride (128 px + 4 pad)
constexpr int XROW = 24, XPS = 348;        // xh row stride / plane stride (dwords)
}

__device__ __forceinline__ unsigned short bf16rne(float f) {
  unsigned u = __float_as_uint(f);
  u += 0x7fffu + ((u >> 16) & 1u);
  return (unsigned short)(u >> 16);
}
__device__ __forceinline__ unsigned packbf2(float a, float b) {
  return (unsigned)bf16rne(a) | ((unsigned)bf16rne(b) << 16);
}

// lgkm-only barrier: LDS producer/consumer ordering WITHOUT draining vmcnt,
// so register-staged global prefetch loads stay in flight across it.
__device__ __forceinline__ void bar_lgkm() {
  asm volatile("s_waitcnt lgkmcnt(0)" ::: "memory");
  __builtin_amdgcn_s_barrier();
}

__global__ __launch_bounds__(256, 2) void invol_fused(
    const float* __restrict__ x, const float* __restrict__ w_reduce,
    const float* __restrict__ w_span, const float* __restrict__ bn_gamma,
    const float* __restrict__ bn_beta, const float* __restrict__ bn_mean,
    const float* __restrict__ bn_var, float* __restrict__ out)
{
  __shared__ __align__(16) unsigned short s_rT[TP * LD];   // 18.4 KB, persists
  __shared__ __align__(16) unsigned short s_a [64 * LD];   // 9.2 KB: wr / w_span slice
  __shared__ __align__(16) float s_u[KKn * WLD];           // 25.9 KB: ph1 xT bf16 / ph2 s_w fp32
  __shared__ __align__(16) float s_xh[16 * XPS];           // 22.3 KB: 16 halo planes

  const int t = threadIdx.x;
  const int lane = t & 63, q = t >> 6;
  const int m16 = lane & 15, quad = lane >> 4;
  const int w0 = blockIdx.x * TW, h0 = blockIdx.y * TH;
  const int b = blockIdx.z;
  const long xbase = (long)b * Cn * HWn;

  // BN constants for this lane's phase-1 D rows (o = q*16 + quad*4 + r)
  float bsc[4], bsh[4];
  {
    int ob = q * 16 + quad * 4;
#pragma unroll
    for (int r = 0; r < 4; ++r) {
      float sc = bn_gamma[ob + r] * rsqrtf(bn_var[ob + r] + 1e-5f);
      bsc[r] = sc;
      bsh[r] = bn_beta[ob + r] - bn_mean[ob + r] * sc;
    }
  }

  // ---------------- Phase 1: rT = bf16(ReLU(BN(w_reduce @ x))) ----------------
  f32x4 pac[8];
#pragma unroll
  for (int pt = 0; pt < 8; ++pt) pac[pt] = (f32x4){0.f, 0.f, 0.f, 0.f};

  unsigned short* xT = (unsigned short*)s_u;  // [128 p][72] bf16

  // staging registers, phase 1 (issued one cc-step ahead, all threads)
  float2 pwr[8];
  float pxa[16], pxb[16];
  auto issue_cc = [&](int cc) {
#pragma unroll
    for (int it = 0; it < 8; ++it) {
      int idx = t + it * 256;
      int o = idx >> 5, cp = idx & 31;
      pwr[it] = *(const float2*)(w_reduce + o * Cn + cc + cp * 2);
    }
#pragma unroll
    for (int it = 0; it < 16; ++it) {
      int idx = t + it * 256;
      int pp = idx & 127, cp = idx >> 7;
      const float* gp = x + xbase + (long)(cc + cp * 2) * HWn
                        + (h0 + (pp >> 4)) * Wn + (w0 + (pp & 15));
      pxa[it] = gp[0];
      pxb[it] = gp[HWn];
    }
  };

  issue_cc(0);
  for (int cc = 0; cc < Cn; cc += 64) {
    bar_lgkm();
#pragma unroll
    for (int it = 0; it < 8; ++it) {        // s_a = w_reduce[o][cc..] bf16
      int idx = t + it * 256;
      int o = idx >> 5, cp = idx & 31;
      ((unsigned*)s_a)[o * LDW + cp] = packbf2(pwr[it].x, pwr[it].y);
    }
#pragma unroll
    for (int it = 0; it < 16; ++it) {       // xT[p][c] bf16 (2 ch packed)
      int idx = t + it * 256;
      int pp = idx & 127, cp = idx >> 7;
      ((unsigned*)xT)[pp * LDW + cp] = packbf2(pxa[it], pxb[it]);
    }
    if (cc + 64 < Cn) issue_cc(cc + 64);    // prefetch next cc-step
    bar_lgkm();
#pragma unroll
    for (int ks = 0; ks < 2; ++ks) {
      bf16x8 af = *(const bf16x8*)(s_a + (q * 16 + m16) * LD + ks * 32 + quad * 8);
#pragma unroll
      for (int pt = 0; pt < 8; ++pt) {
        bf16x8 bf = *(const bf16x8*)(xT + (pt * 16 + m16) * LD + ks * 32 + quad * 8);
        pac[pt] = __builtin_amdgcn_mfma_f32_16x16x32_bf16(af, bf, pac[pt], 0, 0, 0);
      }
    }
  }

  // staging registers, phase 2 -- OWNED BY WAVES 2,3 ONLY (t >= 128).
  // s_a slice: 49 k x 32 float2 = 1568 slots -> 13 iters x 128 threads.
  // halo: 16 planes x 336 (14 rows x 24) = 5376 -> 42 iters x 128 threads.
  float2 pw[13];
  float ph[42];
  auto issue_g = [&](int g) {               // call only when t >= 128
    int u = t - 128;
#pragma unroll
    for (int it = 0; it < 13; ++it) {
      int idx = u + it * 128;
      int k = idx >> 5, op = idx & 31;
      if (k < KKn)
        pw[it] = *(const float2*)(w_span + (long)(g * KKn + k) * CRn + op * 2);
    }
#pragma unroll
    for (int it = 0; it < 42; ++it) {
      int idx = u + it * 128;
      int pl = idx / 336, rem = idx - pl * 336;
      int iy = rem / XROW, ix = rem - iy * XROW;   // ix 22,23: harmless pad
      int gy = h0 + iy - PADn, gx = w0 + ix - PADn;
      float v = 0.f;
      if ((unsigned)gy < (unsigned)Hn && (unsigned)gx < (unsigned)Wn)
        v = x[xbase + (long)(g * CGn + pl) * HWn + gy * Wn + gx];
      ph[it] = v;
    }
  };

  if (t >= 128) issue_g(0);   // overlaps epilogue + first barriers

  // epilogue: BN+ReLU -> rT[p][o] bf16 pairs
#pragma unroll
  for (int pt = 0; pt < 8; ++pt) {
    int pp = pt * 16 + m16;
    float v0 = fmaxf(fmaf(pac[pt][0], bsc[0], bsh[0]), 0.f);
    float v1 = fmaxf(fmaf(pac[pt][1], bsc[1], bsh[1]), 0.f);
    float v2 = fmaxf(fmaf(pac[pt][2], bsc[2], bsh[2]), 0.f);
    float v3 = fmaxf(fmaf(pac[pt][3], bsc[3], bsh[3]), 0.f);
    ((unsigned*)s_rT)[pp * LDW + q * 8 + quad * 2 + 0] = packbf2(v0, v1);
    ((unsigned*)s_rT)[pp * LDW + q * 8 + quad * 2 + 1] = packbf2(v2, v3);
  }

  // ---------------- Phase 2 ----------------
  float* s_w = s_u;                          // [49 k][132] fp32

  // involution lane coords (waves 0,1 only; t < 128):
  //   pg = t>>5 in 0..3 -> planes pg*4 .. pg*4+3 ; slot = t&31 -> 4 px
  const int pg = t >> 5;
  const int islot = t & 31;
  const int ipy = islot >> 2, ipx0 = (islot & 3) * 4;
  const long opix = (h0 + ipy) * Wn + (w0 + ipx0);

  for (int g = 0; g < Gn; ++g) {
    bar_lgkm();  // prior involution reads of s_w/s_xh done; vmcnt stays in flight
    if (t >= 128) {
      int u = t - 128;
#pragma unroll
      for (int it = 0; it < 13; ++it) {     // s_a = w_span[g] slice [k][o] bf16
        int idx = u + it * 128;
        int k = idx >> 5, op = idx & 31;
        if (k < 52) {                       // rows 49..51 zeroed, 52..63 stale-harmless
          unsigned pv = (k < KKn) ? packbf2(pw[it].x, pw[it].y) : 0u;
          ((unsigned*)s_a)[k * LDW + op] = pv;
        }
      }
#pragma unroll
      for (int it = 0; it < 42; ++it) {     // 16 halo planes from staged regs
        int idx = u + it * 128;
        int pl = idx / 336, rem = idx - pl * 336;
        int iy = rem / XROW, ix = rem - iy * XROW;
        s_xh[pl * XPS + iy * XROW + ix] = ph[it];
      }
      if (g + 1 < Gn) issue_g(g + 1);       // prefetch next group
    }
    bar_lgkm();

    // kernel-gen: all 4 waves; wave q -> k-tile q; D[k][p] = w_span @ r
    f32x4 wac[8];
#pragma unroll
    for (int pt = 0; pt < 8; ++pt) wac[pt] = (f32x4){0.f, 0.f, 0.f, 0.f};
#pragma unroll
    for (int ks = 0; ks < 2; ++ks) {
      bf16x8 af = *(const bf16x8*)(s_a + (q * 16 + m16) * LD + ks * 32 + quad * 8);
#pragma unroll
      for (int pt = 0; pt < 8; ++pt) {
        bf16x8 bf = *(const bf16x8*)(s_rT + (pt * 16 + m16) * LD + ks * 32 + quad * 8);
        wac[pt] = __builtin_amdgcn_mfma_f32_16x16x32_bf16(af, bf, wac[pt], 0, 0, 0);
      }
    }
    {
      int kb = q * 16 + quad * 4;
#pragma unroll
      for (int r = 0; r < 4; ++r) {
        if (kb + r < KKn) {
#pragma unroll
          for (int pt = 0; pt < 8; ++pt)
            s_w[(kb + r) * WLD + pt * 16 + m16] = wac[pt][r];
        }
      }
    }
    bar_lgkm();

    // involution: waves 0,1 only -- 4 px x 4 planes per lane.
    if (t < 128) {
      f32x4 a_[4];
#pragma unroll
      for (int pj = 0; pj < 4; ++pj) a_[pj] = (f32x4){0.f, 0.f, 0.f, 0.f};
#pragma unroll 1
      for (int i = 0; i < Kn; ++i) {
        f32x4 wr_[7];
#pragma unroll
        for (int jx = 0; jx < Kn; ++jx)
          wr_[jx] = *(const f32x4*)(s_w + (i * Kn + jx) * WLD + ipy * 16 + ipx0);
#pragma unroll
        for (int pj = 0; pj < 4; ++pj) {
          const float* rp = s_xh + (pg * 4 + pj) * XPS + (ipy + i) * XROW + ipx0;
          f32x4 x0 = *(const f32x4*)rp, x1 = *(const f32x4*)(rp + 4),
                x2 = *(const f32x4*)(rp + 8);
          float xs[12] = {x0[0], x0[1], x0[2], x0[3], x1[0], x1[1], x1[2], x1[3],
                          x2[0], x2[1], x2[2], x2[3]};
#pragma unroll
          for (int jx = 0; jx < Kn; ++jx) {
#pragma unroll
            for (int j = 0; j < 4; ++j)
              a_[pj][j] = fmaf(wr_[jx][j], xs[jx + j], a_[pj][j]);
          }
        }
      }
      float* ob = out + xbase + (long)(g * CGn + pg * 4) * HWn + opix;
#pragma unroll
      for (int pj = 0; pj < 4; ++pj)
        *(f32x4*)(ob + (long)pj * HWn) = a_[pj];
    }
  }
}

extern "C" void kernel_launch(void* const* d_in, const int* in_sizes, int n_in,
                              void* d_out, int out_size, void* d_ws, size_t ws_size,
                              hipStream_t stream) {
  const float* x        = (const float*)d_in[0];
  const float* w_reduce = (const float*)d_in[1];
  const float* w_span   = (const float*)d_in[2];
  const float* bn_gamma = (const float*)d_in[3];
  const float* bn_beta  = (const float*)d_in[4];
  const float* bn_mean  = (const float*)d_in[5];
  const float* bn_var   = (const float*)d_in[6];
  float* outp = (float*)d_out;

  dim3 grid(Wn / TW, Hn / TH, 16);  // 4 x 8 x 16 = 512 blocks, 2/CU
  invol_fused<<<grid, 256, 0, stream>>>(x, w_reduce, w_span, bn_gamma,
                                        bn_beta, bn_mean, bn_var, outp);
}

// Round 5
// 197.301 us; speedup vs baseline: 2.3851x; 2.3851x over previous
//
#include <hip/hip_runtime.h>

// Involution2d fused, MFMA + sliding-window involution.
// Block = (batch, 8-row x 16-col tile), 256 threads / 4 waves, 2 blocks/CU.
// Phase 1: rT[p][o] = bf16(ReLU(BN(w_reduce @ x)))   via mfma 16x16x32 bf16
// Phase 2 per group: kernel-gen MFMA -> s_w[k][p] fp32; involution.
// R2: lgkm-only barriers + register-staged prefetch (2x win, latency-bound fix).
// R4 FAILED: wave-specialized STAGING (68 live regs in waves 2-3) spilled to
//   scratch: FETCH +120MB, WRITE +52MB, 3.6x slower. Reverted.
// R5: staging back to all-256-threads (pw[8]+ph[21], proven spill-free at
//   VGPR 116). Keep only the involution COMPUTE specialization: waves 0,1
//   do 4 px x 4 planes per lane (s_w weight reads halve, and both
//   half-waves read identical weight addresses -> broadcast); waves 2,3
//   idle through the involution (LDS is the saturated pipe, not VALU).

typedef __attribute__((ext_vector_type(8))) short bf16x8;
typedef __attribute__((ext_vector_type(4))) float f32x4;

namespace {
constexpr int Cn = 256, Hn = 64, Wn = 64, HWn = 4096;
constexpr int Gn = 16, CGn = 16, CRn = 64;
constexpr int Kn = 7, PADn = 3, KKn = 49;
constexpr int TH = 8, TW = 16, TP = 128;   // tile pixels
constexpr int LD = 72, LDW = 36;           // bf16 row stride (64 + 8 pad) / dwords
constexpr int WLD = 132;                   // s_w fp32 row stride (128 px + 4 pad)
constexpr int XROW = 24, XPS = 348;        // xh row stride / plane stride (dwords)
}

__device__ __forceinline__ unsigned short bf16rne(float f) {
  unsigned u = __float_as_uint(f);
  u += 0x7fffu + ((u >> 16) & 1u);
  return (unsigned short)(u >> 16);
}
__device__ __forceinline__ unsigned packbf2(float a, float b) {
  return (unsigned)bf16rne(a) | ((unsigned)bf16rne(b) << 16);
}

// lgkm-only barrier: LDS producer/consumer ordering WITHOUT draining vmcnt,
// so register-staged global prefetch loads stay in flight across it.
__device__ __forceinline__ void bar_lgkm() {
  asm volatile("s_waitcnt lgkmcnt(0)" ::: "memory");
  __builtin_amdgcn_s_barrier();
}

__global__ __launch_bounds__(256, 2) void invol_fused(
    const float* __restrict__ x, const float* __restrict__ w_reduce,
    const float* __restrict__ w_span, const float* __restrict__ bn_gamma,
    const float* __restrict__ bn_beta, const float* __restrict__ bn_mean,
    const float* __restrict__ bn_var, float* __restrict__ out)
{
  __shared__ __align__(16) unsigned short s_rT[TP * LD];   // 18.4 KB, persists
  __shared__ __align__(16) unsigned short s_a [64 * LD];   // 9.2 KB: wr / w_span slice
  __shared__ __align__(16) float s_u[KKn * WLD];           // 25.9 KB: ph1 xT bf16 / ph2 s_w fp32
  __shared__ __align__(16) float s_xh[16 * XPS];           // 22.3 KB: 16 halo planes

  const int t = threadIdx.x;
  const int lane = t & 63, q = t >> 6;
  const int m16 = lane & 15, quad = lane >> 4;
  const int w0 = blockIdx.x * TW, h0 = blockIdx.y * TH;
  const int b = blockIdx.z;
  const long xbase = (long)b * Cn * HWn;

  // BN constants for this lane's phase-1 D rows (o = q*16 + quad*4 + r)
  float bsc[4], bsh[4];
  {
    int ob = q * 16 + quad * 4;
#pragma unroll
    for (int r = 0; r < 4; ++r) {
      float sc = bn_gamma[ob + r] * rsqrtf(bn_var[ob + r] + 1e-5f);
      bsc[r] = sc;
      bsh[r] = bn_beta[ob + r] - bn_mean[ob + r] * sc;
    }
  }

  // ---------------- Phase 1: rT = bf16(ReLU(BN(w_reduce @ x))) ----------------
  f32x4 pac[8];
#pragma unroll
  for (int pt = 0; pt < 8; ++pt) pac[pt] = (f32x4){0.f, 0.f, 0.f, 0.f};

  unsigned short* xT = (unsigned short*)s_u;  // [128 p][72] bf16

  // staging registers, phase 1 (issued one cc-step ahead, all threads)
  float2 pwr[8];
  float pxa[16], pxb[16];
  auto issue_cc = [&](int cc) {
#pragma unroll
    for (int it = 0; it < 8; ++it) {
      int idx = t + it * 256;
      int o = idx >> 5, cp = idx & 31;
      pwr[it] = *(const float2*)(w_reduce + o * Cn + cc + cp * 2);
    }
#pragma unroll
    for (int it = 0; it < 16; ++it) {
      int idx = t + it * 256;
      int pp = idx & 127, cp = idx >> 7;
      const float* gp = x + xbase + (long)(cc + cp * 2) * HWn
                        + (h0 + (pp >> 4)) * Wn + (w0 + (pp & 15));
      pxa[it] = gp[0];
      pxb[it] = gp[HWn];
    }
  };

  issue_cc(0);
  for (int cc = 0; cc < Cn; cc += 64) {
    bar_lgkm();
#pragma unroll
    for (int it = 0; it < 8; ++it) {        // s_a = w_reduce[o][cc..] bf16
      int idx = t + it * 256;
      int o = idx >> 5, cp = idx & 31;
      ((unsigned*)s_a)[o * LDW + cp] = packbf2(pwr[it].x, pwr[it].y);
    }
#pragma unroll
    for (int it = 0; it < 16; ++it) {       // xT[p][c] bf16 (2 ch packed)
      int idx = t + it * 256;
      int pp = idx & 127, cp = idx >> 7;
      ((unsigned*)xT)[pp * LDW + cp] = packbf2(pxa[it], pxb[it]);
    }
    if (cc + 64 < Cn) issue_cc(cc + 64);    // prefetch next cc-step
    bar_lgkm();
#pragma unroll
    for (int ks = 0; ks < 2; ++ks) {
      bf16x8 af = *(const bf16x8*)(s_a + (q * 16 + m16) * LD + ks * 32 + quad * 8);
#pragma unroll
      for (int pt = 0; pt < 8; ++pt) {
        bf16x8 bf = *(const bf16x8*)(xT + (pt * 16 + m16) * LD + ks * 32 + quad * 8);
        pac[pt] = __builtin_amdgcn_mfma_f32_16x16x32_bf16(af, bf, pac[pt], 0, 0, 0);
      }
    }
  }

  // staging registers, phase 2 (issued one group ahead, ALL 256 threads --
  // R2 distribution, 37 live regs, proven spill-free)
  float2 pw[8];
  float ph[21];
  auto issue_g = [&](int g) {
#pragma unroll
    for (int it = 0; it < 8; ++it) {        // w_span[g] slice
      int idx = t + it * 256;
      int k = idx >> 5, op = idx & 31;
      if (k < KKn)
        pw[it] = *(const float2*)(w_span + (long)(g * KKn + k) * CRn + op * 2);
    }
#pragma unroll
    for (int it = 0; it < 21; ++it) {       // 16 halo planes (16*336 = 21*256)
      int idx = t + it * 256;
      int pl = idx / 336, rem = idx - pl * 336;
      int iy = rem / XROW, ix = rem - iy * XROW;   // ix 22,23: harmless pad
      int gy = h0 + iy - PADn, gx = w0 + ix - PADn;
      float v = 0.f;
      if ((unsigned)gy < (unsigned)Hn && (unsigned)gx < (unsigned)Wn)
        v = x[xbase + (long)(g * CGn + pl) * HWn + gy * Wn + gx];
      ph[it] = v;
    }
  };

  issue_g(0);  // overlaps epilogue + first barriers

  // epilogue: BN+ReLU -> rT[p][o] bf16 pairs
#pragma unroll
  for (int pt = 0; pt < 8; ++pt) {
    int pp = pt * 16 + m16;
    float v0 = fmaxf(fmaf(pac[pt][0], bsc[0], bsh[0]), 0.f);
    float v1 = fmaxf(fmaf(pac[pt][1], bsc[1], bsh[1]), 0.f);
    float v2 = fmaxf(fmaf(pac[pt][2], bsc[2], bsh[2]), 0.f);
    float v3 = fmaxf(fmaf(pac[pt][3], bsc[3], bsh[3]), 0.f);
    ((unsigned*)s_rT)[pp * LDW + q * 8 + quad * 2 + 0] = packbf2(v0, v1);
    ((unsigned*)s_rT)[pp * LDW + q * 8 + quad * 2 + 1] = packbf2(v2, v3);
  }

  // ---------------- Phase 2 ----------------
  float* s_w = s_u;                          // [49 k][132] fp32

  // involution lane coords (waves 0,1 only; t < 128):
  //   pg = t>>5 in 0..3 -> planes pg*4 .. pg*4+3 ; islot = t&31 -> 4 px
  const int pg = t >> 5;
  const int islot = t & 31;
  const int ipy = islot >> 2, ipx0 = (islot & 3) * 4;
  const long opix = (h0 + ipy) * Wn + (w0 + ipx0);

  for (int g = 0; g < Gn; ++g) {
    bar_lgkm();  // prior involution reads of s_w/s_xh done; vmcnt stays in flight
#pragma unroll
    for (int it = 0; it < 8; ++it) {        // s_a = w_span[g] slice [k][o] bf16
      int idx = t + it * 256;
      int k = idx >> 5, op = idx & 31;
      unsigned pv = (k < KKn) ? packbf2(pw[it].x, pw[it].y) : 0u;
      ((unsigned*)s_a)[k * LDW + op] = pv;
    }
#pragma unroll
    for (int it = 0; it < 21; ++it) {       // 16 halo planes from staged regs
      int idx = t + it * 256;
      int pl = idx / 336, rem = idx - pl * 336;
      int iy = rem / XROW, ix = rem - iy * XROW;
      s_xh[pl * XPS + iy * XROW + ix] = ph[it];
    }
    if (g + 1 < Gn) issue_g(g + 1);         // prefetch next group
    bar_lgkm();

    // kernel-gen: all 4 waves; wave q -> k-tile q; D[k][p] = w_span @ r
    f32x4 wac[8];
#pragma unroll
    for (int pt = 0; pt < 8; ++pt) wac[pt] = (f32x4){0.f, 0.f, 0.f, 0.f};
#pragma unroll
    for (int ks = 0; ks < 2; ++ks) {
      bf16x8 af = *(const bf16x8*)(s_a + (q * 16 + m16) * LD + ks * 32 + quad * 8);
#pragma unroll
      for (int pt = 0; pt < 8; ++pt) {
        bf16x8 bf = *(const bf16x8*)(s_rT + (pt * 16 + m16) * LD + ks * 32 + quad * 8);
        wac[pt] = __builtin_amdgcn_mfma_f32_16x16x32_bf16(af, bf, wac[pt], 0, 0, 0);
      }
    }
    {
      int kb = q * 16 + quad * 4;
#pragma unroll
      for (int r = 0; r < 4; ++r) {
        if (kb + r < KKn) {
#pragma unroll
          for (int pt = 0; pt < 8; ++pt)
            s_w[(kb + r) * WLD + pt * 16 + m16] = wac[pt][r];
        }
      }
    }
    bar_lgkm();

    // involution: waves 0,1 only -- 4 px x 4 planes per lane.
    // Weight b128 reads: address = f(islot) only -> both half-waves
    // broadcast the same line; total s_w read volume halves vs R2.
    if (t < 128) {
      f32x4 a_[4];
#pragma unroll
      for (int pj = 0; pj < 4; ++pj) a_[pj] = (f32x4){0.f, 0.f, 0.f, 0.f};
#pragma unroll 1
      for (int i = 0; i < Kn; ++i) {
        f32x4 wr_[7];
#pragma unroll
        for (int jx = 0; jx < Kn; ++jx)
          wr_[jx] = *(const f32x4*)(s_w + (i * Kn + jx) * WLD + ipy * 16 + ipx0);
#pragma unroll
        for (int pj = 0; pj < 4; ++pj) {
          const float* rp = s_xh + (pg * 4 + pj) * XPS + (ipy + i) * XROW + ipx0;
          f32x4 x0 = *(const f32x4*)rp, x1 = *(const f32x4*)(rp + 4),
                x2 = *(const f32x4*)(rp + 8);
          float xs[12] = {x0[0], x0[1], x0[2], x0[3], x1[0], x1[1], x1[2], x1[3],
                          x2[0], x2[1], x2[2], x2[3]};
#pragma unroll
          for (int jx = 0; jx < Kn; ++jx) {
#pragma unroll
            for (int j = 0; j < 4; ++j)
              a_[pj][j] = fmaf(wr_[jx][j], xs[jx + j], a_[pj][j]);
          }
        }
      }
      float* ob = out + xbase + (long)(g * CGn + pg * 4) * HWn + opix;
#pragma unroll
      for (int pj = 0; pj < 4; ++pj)
        *(f32x4*)(ob + (long)pj * HWn) = a_[pj];
    }
  }
}

extern "C" void kernel_launch(void* const* d_in, const int* in_sizes, int n_in,
                              void* d_out, int out_size, void* d_ws, size_t ws_size,
                              hipStream_t stream) {
  const float* x        = (const float*)d_in[0];
  const float* w_reduce = (const float*)d_in[1];
  const float* w_span   = (const float*)d_in[2];
  const float* bn_gamma = (const float*)d_in[3];
  const float* bn_beta  = (const float*)d_in[4];
  const float* bn_mean  = (const float*)d_in[5];
  const float* bn_var   = (const float*)d_in[6];
  float* outp = (float*)d_out;

  dim3 grid(Wn / TW, Hn / TH, 16);  // 4 x 8 x 16 = 512 blocks, 2/CU
  invol_fused<<<grid, 256, 0, stream>>>(x, w_reduce, w_span, bn_gamma,
                                        bn_beta, bn_mean, bn_var, outp);
}

// Round 7
// 188.782 us; speedup vs baseline: 2.4927x; 1.0451x over previous
//
#include <hip/hip_runtime.h>

// Involution2d fused, MFMA + sliding-window involution.
// Block = (batch, 8-row x 16-col tile), 256 threads / 4 waves, 2 blocks/CU.
// Phase 1: rT[p][o] = bf16(ReLU(BN(w_reduce @ x)))   via mfma 16x16x32 bf16
// Phase 2 per group: kernel-gen MFMA -> s_w[k][p] fp32; involution 4px x
//   2 planes per lane across all 4 waves (R2 form; R5's 2-wave concentration
//   was issue-bound and slower).
// R2: lgkm-only barriers + register-staged prefetch (300->106us).
// R4 FAILED: staging concentrated in waves 2,3 -> spills (FETCH +120MB).
// R5 NEUTRAL-NEG: 2-wave involution halved s_w reads but doubled per-wave
//   issue -> LDS volume is NOT binding; phase serialization is.
// R6: structural de-serialization, math bitwise-identical:
//   - s_a ELIMINATED: MFMA A-fragments (w_reduce / w_span slices) are
//     lane-private -> prefetch to regs + pack bf16 in-place. Removes the
//     staging->kgen dependency, so stage-writes and kgen merge into ONE
//     phase: 3 barriers/group -> 2.
//   - Linear halo staging: XPS=336 so LDS offset == staged idx (no div/mod
//     in write loop; 21*256 == 16*336 exact).

typedef __attribute__((ext_vector_type(8))) short bf16x8;
typedef __attribute__((ext_vector_type(4))) float f32x4;

namespace {
constexpr int Cn = 256, Hn = 64, Wn = 64, HWn = 4096;
constexpr int Gn = 16, CGn = 16, CRn = 64;
constexpr int Kn = 7, PADn = 3, KKn = 49;
constexpr int TH = 8, TW = 16, TP = 128;   // tile pixels
constexpr int LD = 72, LDW = 36;           // bf16 row stride (64 + 8 pad) / dwords
constexpr int WLD = 132;                   // s_w fp32 row stride (128 px + 4 pad)
constexpr int XROW = 24, XPS = 336;        // halo row / plane stride (dwords); linear
}

__device__ __forceinline__ unsigned short bf16rne(float f) {
  unsigned u = __float_as_uint(f);
  u += 0x7fffu + ((u >> 16) & 1u);
  return (unsigned short)(u >> 16);
}
__device__ __forceinline__ unsigned packbf2(float a, float b) {
  return (unsigned)bf16rne(a) | ((unsigned)bf16rne(b) << 16);
}

// lgkm-only barrier: LDS producer/consumer ordering WITHOUT draining vmcnt,
// so register-staged global prefetch loads stay in flight across it.
__device__ __forceinline__ void bar_lgkm() {
  asm volatile("s_waitcnt lgkmcnt(0)" ::: "memory");
  __builtin_amdgcn_s_barrier();
}

__global__ __launch_bounds__(256, 2) void invol_fused(
    const float* __restrict__ x, const float* __restrict__ w_reduce,
    const float* __restrict__ w_span, const float* __restrict__ bn_gamma,
    const float* __restrict__ bn_beta, const float* __restrict__ bn_mean,
    const float* __restrict__ bn_var, float* __restrict__ out)
{
  __shared__ __align__(16) unsigned short s_rT[TP * LD];   // 18.4 KB, persists
  __shared__ __align__(16) float s_u[KKn * WLD];           // 25.9 KB: ph1 xT bf16 / ph2 s_w fp32
  __shared__ __align__(16) float s_xh[16 * XPS];           // 21.5 KB: 16 halo planes, linear

  const int t = threadIdx.x;
  const int lane = t & 63, q = t >> 6;
  const int m16 = lane & 15, quad = lane >> 4;
  const int s = lane >> 5;                 // half of wave -> cg split
  const int slot = lane & 31;
  const int py = slot >> 2, px0 = (slot & 3) * 4;
  const int w0 = blockIdx.x * TW, h0 = blockIdx.y * TH;
  const int b = blockIdx.z;
  const long xbase = (long)b * Cn * HWn;

  // BN constants for this lane's phase-1 D rows (o = q*16 + quad*4 + r)
  float bsc[4], bsh[4];
  {
    int ob = q * 16 + quad * 4;
#pragma unroll
    for (int r = 0; r < 4; ++r) {
      float sc = bn_gamma[ob + r] * rsqrtf(bn_var[ob + r] + 1e-5f);
      bsc[r] = sc;
      bsh[r] = bn_beta[ob + r] - bn_mean[ob + r] * sc;
    }
  }

  // ---------------- Phase 1: rT = bf16(ReLU(BN(w_reduce @ x))) ----------------
  f32x4 pac[8];
#pragma unroll
  for (int pt = 0; pt < 8; ++pt) pac[pt] = (f32x4){0.f, 0.f, 0.f, 0.f};

  unsigned short* xT = (unsigned short*)s_u;  // [128 p][72] bf16

  // staging: x-tile to regs (all threads) + lane-private A-fragment regs
  float pxa[16], pxb[16];
  f32x4 pA1[4];
  const float* wrrow = w_reduce + (q * 16 + m16) * Cn;   // this lane's A row

  auto issue_cc = [&](int cc) {
#pragma unroll
    for (int h = 0; h < 4; ++h)   // A frag: cols cc + ks*32 + quad*8 + h4
      pA1[h] = *(const f32x4*)(wrrow + cc + (h >> 1) * 32 + quad * 8 + (h & 1) * 4);
#pragma unroll
    for (int it = 0; it < 16; ++it) {
      int idx = t + it * 256;
      int pp = idx & 127, cp = idx >> 7;
      const float* gp = x + xbase + (long)(cc + cp * 2) * HWn
                        + (h0 + (pp >> 4)) * Wn + (w0 + (pp & 15));
      pxa[it] = gp[0];
      pxb[it] = gp[HWn];
    }
  };

  issue_cc(0);
  for (int cc = 0; cc < Cn; cc += 64) {
    bar_lgkm();
#pragma unroll
    for (int it = 0; it < 16; ++it) {       // xT[p][c] bf16 (2 ch packed)
      int idx = t + it * 256;
      int pp = idx & 127, cp = idx >> 7;
      ((unsigned*)xT)[pp * LDW + cp] = packbf2(pxa[it], pxb[it]);
    }
    bf16x8 afr[2];                          // pack A-frag before regs reused
#pragma unroll
    for (int ks = 0; ks < 2; ++ks) {
      unsigned* ap = (unsigned*)&afr[ks];
      f32x4 lo = pA1[ks * 2], hi = pA1[ks * 2 + 1];
      ap[0] = packbf2(lo[0], lo[1]); ap[1] = packbf2(lo[2], lo[3]);
      ap[2] = packbf2(hi[0], hi[1]); ap[3] = packbf2(hi[2], hi[3]);
    }
    if (cc + 64 < Cn) issue_cc(cc + 64);    // prefetch next cc-step
    bar_lgkm();
#pragma unroll
    for (int ks = 0; ks < 2; ++ks) {
#pragma unroll
      for (int pt = 0; pt < 8; ++pt) {
        bf16x8 bf = *(const bf16x8*)(xT + (pt * 16 + m16) * LD + ks * 32 + quad * 8);
        pac[pt] = __builtin_amdgcn_mfma_f32_16x16x32_bf16(afr[ks], bf, pac[pt], 0, 0, 0);
      }
    }
  }

  // phase-2 staging regs (all 256 threads; proven spill-free scale)
  float ph[21];
  f32x4 pA2[4];
  const int wrow = q * 16 + m16;            // A row for kgen (rows>=49 discarded)
  auto issue_g = [&](int g) {
    const float* wsrow = w_span + ((long)g * KKn + (wrow < KKn ? wrow : 0)) * CRn;
#pragma unroll
    for (int h = 0; h < 4; ++h)
      pA2[h] = *(const f32x4*)(wsrow + (h >> 1) * 32 + quad * 8 + (h & 1) * 4);
#pragma unroll
    for (int it = 0; it < 21; ++it) {       // 16 planes x 336 == 21*256 exact
      int idx = t + it * 256;
      int pl = idx / 336, rem = idx - pl * 336;
      int iy = rem / XROW, ix = rem - iy * XROW;   // ix 22,23: harmless pad
      int gy = h0 + iy - PADn, gx = w0 + ix - PADn;
      float v = 0.f;
      if ((unsigned)gy < (unsigned)Hn && (unsigned)gx < (unsigned)Wn)
        v = x[xbase + (long)(g * CGn + pl) * HWn + gy * Wn + gx];
      ph[it] = v;
    }
  };

  issue_g(0);  // loads fly over epilogue + pre-loop barrier

  // epilogue: BN+ReLU -> rT[p][o] bf16 pairs
#pragma unroll
  for (int pt = 0; pt < 8; ++pt) {
    int pp = pt * 16 + m16;
    float v0 = fmaxf(fmaf(pac[pt][0], bsc[0], bsh[0]), 0.f);
    float v1 = fmaxf(fmaf(pac[pt][1], bsc[1], bsh[1]), 0.f);
    float v2 = fmaxf(fmaf(pac[pt][2], bsc[2], bsh[2]), 0.f);
    float v3 = fmaxf(fmaf(pac[pt][3], bsc[3], bsh[3]), 0.f);
    ((unsigned*)s_rT)[pp * LDW + q * 8 + quad * 2 + 0] = packbf2(v0, v1);
    ((unsigned*)s_rT)[pp * LDW + q * 8 + quad * 2 + 1] = packbf2(v2, v3);
  }

  // ---------------- Phase 2: 2 barriers per group ----------------
  float* s_w = s_u;                          // [49 k][132] fp32
  const int cgA = q + 4 * s;                 // this lane's 2 cg planes
  const int cgB = cgA + 8;
  const float* plA = s_xh + cgA * XPS;
  const float* plB = s_xh + cgB * XPS;
  const long opix = (h0 + py) * Wn + (w0 + px0);

  bar_lgkm();  // s_rT visible to all; xT(s_u) reads drained before s_w writes

  for (int g = 0; g < Gn; ++g) {
    // ---- P0: halo writes + kernel-gen (A-frag from regs) -> s_w ----
#pragma unroll
    for (int it = 0; it < 21; ++it)          // linear: LDS offset == idx
      s_xh[t + it * 256] = ph[it];

    bf16x8 afr2[2];
#pragma unroll
    for (int ks = 0; ks < 2; ++ks) {
      unsigned* ap = (unsigned*)&afr2[ks];
      f32x4 lo = pA2[ks * 2], hi = pA2[ks * 2 + 1];
      ap[0] = packbf2(lo[0], lo[1]); ap[1] = packbf2(lo[2], lo[3]);
      ap[2] = packbf2(hi[0], hi[1]); ap[3] = packbf2(hi[2], hi[3]);
    }

    f32x4 wac[8];
#pragma unroll
    for (int pt = 0; pt < 8; ++pt) wac[pt] = (f32x4){0.f, 0.f, 0.f, 0.f};
#pragma unroll
    for (int ks = 0; ks < 2; ++ks) {
#pragma unroll
      for (int pt = 0; pt < 8; ++pt) {
        bf16x8 bf = *(const bf16x8*)(s_rT + (pt * 16 + m16) * LD + ks * 32 + quad * 8);
        wac[pt] = __builtin_amdgcn_mfma_f32_16x16x32_bf16(afr2[ks], bf, wac[pt], 0, 0, 0);
      }
    }
    {
      int kb = q * 16 + quad * 4;
#pragma unroll
      for (int r = 0; r < 4; ++r) {
        if (kb + r < KKn) {
#pragma unroll
          for (int pt = 0; pt < 8; ++pt)
            s_w[(kb + r) * WLD + pt * 16 + m16] = wac[pt][r];
        }
      }
    }
    bar_lgkm();

    // ---- P1: prefetch g+1 (flies over barriers) + involution ----
    if (g + 1 < Gn) issue_g(g + 1);

    f32x4 a0 = (f32x4){0.f, 0.f, 0.f, 0.f};
    f32x4 a1 = (f32x4){0.f, 0.f, 0.f, 0.f};
#pragma unroll 1
    for (int i = 0; i < Kn; ++i) {
      f32x4 wr_[7];
#pragma unroll
      for (int jx = 0; jx < Kn; ++jx)
        wr_[jx] = *(const f32x4*)(s_w + (i * Kn + jx) * WLD + py * 16 + px0);
      const float* rA = plA + (py + i) * XROW + px0;
      const float* rB = plB + (py + i) * XROW + px0;
      f32x4 xa0 = *(const f32x4*)rA, xa1 = *(const f32x4*)(rA + 4), xa2 = *(const f32x4*)(rA + 8);
      f32x4 xb0 = *(const f32x4*)rB, xb1 = *(const f32x4*)(rB + 4), xb2 = *(const f32x4*)(rB + 8);
      float xa[12] = {xa0[0], xa0[1], xa0[2], xa0[3], xa1[0], xa1[1], xa1[2], xa1[3],
                      xa2[0], xa2[1], xa2[2], xa2[3]};
      float xb[12] = {xb0[0], xb0[1], xb0[2], xb0[3], xb1[0], xb1[1], xb1[2], xb1[3],
                      xb2[0], xb2[1], xb2[2], xb2[3]};
#pragma unroll
      for (int jx = 0; jx < Kn; ++jx) {
#pragma unroll
        for (int j = 0; j < 4; ++j) {
          a0[j] = fmaf(wr_[jx][j], xa[jx + j], a0[j]);
          a1[j] = fmaf(wr_[jx][j], xb[jx + j], a1[j]);
        }
      }
    }
    float* ob = out + xbase + (long)(g * CGn) * HWn + opix;
    *(f32x4*)(ob + (long)cgA * HWn) = a0;
    *(f32x4*)(ob + (long)cgB * HWn) = a1;

    bar_lgkm();  // invol reads of s_w/s_xh drained before next P0 overwrites
  }
}

extern "C" void kernel_launch(void* const* d_in, const int* in_sizes, int n_in,
                              void* d_out, int out_size, void* d_ws, size_t ws_size,
                              hipStream_t stream) {
  const float* x        = (const float*)d_in[0];
  const float* w_reduce = (const float*)d_in[1];
  const float* w_span   = (const float*)d_in[2];
  const float* bn_gamma = (const float*)d_in[3];
  const float* bn_beta  = (const float*)d_in[4];
  const float* bn_mean  = (const float*)d_in[5];
  const float* bn_var   = (const float*)d_in[6];
  float* outp = (float*)d_out;

  dim3 grid(Wn / TW, Hn / TH, 16);  // 4 x 8 x 16 = 512 blocks, 2/CU
  invol_fused<<<grid, 256, 0, stream>>>(x, w_reduce, w_span, bn_gamma,
                                        bn_beta, bn_mean, bn_var, outp);
}

// Round 8
// 176.746 us; speedup vs baseline: 2.6624x; 1.0681x over previous
//
#include <hip/hip_runtime.h>

// Involution2d fused, MFMA + sliding-window involution.
// Block = (batch, 8-row x 16-col tile), 256 threads / 4 waves, 2 blocks/CU.
// Phase 1: rT[p][o] = bf16(ReLU(BN(w_reduce @ x)))   via mfma 16x16x32 bf16
// Phase 2 per group: P0 {halo LDS writes + kernel-gen MFMA -> s_w} / bar /
//   P1 {prefetch g+1 + involution 4px x 2 planes per lane, all 4 waves} / bar.
// R2: lgkm-only barriers + register-staged prefetch (300->106us).
// R4 FAILED: staging concentrated in waves 2,3 -> spills (FETCH +120MB).
// R5 NEG: LDS read volume is not binding (volume -25% -> slower).
// R7: s_a eliminated (A-frags lane-private), 2 barriers/group (106->101us).
// R8: counters show no pipe >40% yet time flat -> block critical path waits
//     on halo prefetch HBM returns (FETCH 230MB = 3.4x of x; slabs fetched
//     per-XCD redundantly). Fix: XCD-aware block swizzle - batch b lands
//     entirely on XCD b%8 (32 blocks = 1 batch fills an XCD at 2/CU), so
//     each group's 256KB x-slab is fetched once per XCD and halo loads
//     become L2 hits (~200cy, covered by involution). Also hoisted the
//     g-invariant halo addressing (div/mod/bounds) into hoff[21].

typedef __attribute__((ext_vector_type(8))) short bf16x8;
typedef __attribute__((ext_vector_type(4))) float f32x4;

namespace {
constexpr int Cn = 256, Hn = 64, Wn = 64, HWn = 4096;
constexpr int Gn = 16, CGn = 16, CRn = 64;
constexpr int Kn = 7, PADn = 3, KKn = 49;
constexpr int TH = 8, TW = 16, TP = 128;   // tile pixels
constexpr int LD = 72, LDW = 36;           // bf16 row stride (64 + 8 pad) / dwords
constexpr int WLD = 132;                   // s_w fp32 row stride (128 px + 4 pad)
constexpr int XROW = 24, XPS = 336;        // halo row / plane stride (dwords); linear
}

__device__ __forceinline__ unsigned short bf16rne(float f) {
  unsigned u = __float_as_uint(f);
  u += 0x7fffu + ((u >> 16) & 1u);
  return (unsigned short)(u >> 16);
}
__device__ __forceinline__ unsigned packbf2(float a, float b) {
  return (unsigned)bf16rne(a) | ((unsigned)bf16rne(b) << 16);
}

// lgkm-only barrier: LDS producer/consumer ordering WITHOUT draining vmcnt,
// so register-staged global prefetch loads stay in flight across it.
__device__ __forceinline__ void bar_lgkm() {
  asm volatile("s_waitcnt lgkmcnt(0)" ::: "memory");
  __builtin_amdgcn_s_barrier();
}

__global__ __launch_bounds__(256, 2) void invol_fused(
    const float* __restrict__ x, const float* __restrict__ w_reduce,
    const float* __restrict__ w_span, const float* __restrict__ bn_gamma,
    const float* __restrict__ bn_beta, const float* __restrict__ bn_mean,
    const float* __restrict__ bn_var, float* __restrict__ out)
{
  __shared__ __align__(16) unsigned short s_rT[TP * LD];   // 18.4 KB, persists
  __shared__ __align__(16) float s_u[KKn * WLD];           // 25.9 KB: ph1 xT bf16 / ph2 s_w fp32
  __shared__ __align__(16) float s_xh[16 * XPS];           // 21.5 KB: 16 halo planes, linear

  const int t = threadIdx.x;
  const int lane = t & 63, q = t >> 6;
  const int m16 = lane & 15, quad = lane >> 4;
  const int s = lane >> 5;                 // half of wave -> cg split
  const int slot = lane & 31;
  const int py = slot >> 2, px0 = (slot & 3) * 4;

  // XCD-aware block swizzle: hardware assigns XCD ~ (blockIdx.x % 8).
  // Batch b -> XCD b&7 (two batches per XCD); 32 tiles of a batch stay
  // together on one XCD's L2 so group x-slabs are fetched once per XCD.
  const int bid = blockIdx.x;              // 0..511
  const int xcd = bid & 7;
  const int jj  = bid >> 3;                // 0..63 within XCD
  const int b   = xcd + 8 * (jj >> 5);     // batches {xcd, xcd+8}
  const int tile = jj & 31;                // 0..31 -> 8x4 tile grid
  const int h0 = (tile >> 2) * TH;
  const int w0 = (tile & 3) * TW;
  const long xbase = (long)b * Cn * HWn;

  // BN constants for this lane's phase-1 D rows (o = q*16 + quad*4 + r)
  float bsc[4], bsh[4];
  {
    int ob = q * 16 + quad * 4;
#pragma unroll
    for (int r = 0; r < 4; ++r) {
      float sc = bn_gamma[ob + r] * rsqrtf(bn_var[ob + r] + 1e-5f);
      bsc[r] = sc;
      bsh[r] = bn_beta[ob + r] - bn_mean[ob + r] * sc;
    }
  }

  // ---------------- Phase 1: rT = bf16(ReLU(BN(w_reduce @ x))) ----------------
  f32x4 pac[8];
#pragma unroll
  for (int pt = 0; pt < 8; ++pt) pac[pt] = (f32x4){0.f, 0.f, 0.f, 0.f};

  unsigned short* xT = (unsigned short*)s_u;  // [128 p][72] bf16

  // staging: x-tile to regs (all threads) + lane-private A-fragment regs
  float pxa[16], pxb[16];
  f32x4 pA1[4];
  const float* wrrow = w_reduce + (q * 16 + m16) * Cn;   // this lane's A row

  auto issue_cc = [&](int cc) {
#pragma unroll
    for (int h = 0; h < 4; ++h)   // A frag: cols cc + ks*32 + quad*8 + h4
      pA1[h] = *(const f32x4*)(wrrow + cc + (h >> 1) * 32 + quad * 8 + (h & 1) * 4);
#pragma unroll
    for (int it = 0; it < 16; ++it) {
      int idx = t + it * 256;
      int pp = idx & 127, cp = idx >> 7;
      const float* gp = x + xbase + (long)(cc + cp * 2) * HWn
                        + (h0 + (pp >> 4)) * Wn + (w0 + (pp & 15));
      pxa[it] = gp[0];
      pxb[it] = gp[HWn];
    }
  };

  issue_cc(0);
  for (int cc = 0; cc < Cn; cc += 64) {
    bar_lgkm();
#pragma unroll
    for (int it = 0; it < 16; ++it) {       // xT[p][c] bf16 (2 ch packed)
      int idx = t + it * 256;
      int pp = idx & 127, cp = idx >> 7;
      ((unsigned*)xT)[pp * LDW + cp] = packbf2(pxa[it], pxb[it]);
    }
    bf16x8 afr[2];                          // pack A-frag before regs reused
#pragma unroll
    for (int ks = 0; ks < 2; ++ks) {
      unsigned* ap = (unsigned*)&afr[ks];
      f32x4 lo = pA1[ks * 2], hi = pA1[ks * 2 + 1];
      ap[0] = packbf2(lo[0], lo[1]); ap[1] = packbf2(lo[2], lo[3]);
      ap[2] = packbf2(hi[0], hi[1]); ap[3] = packbf2(hi[2], hi[3]);
    }
    if (cc + 64 < Cn) issue_cc(cc + 64);    // prefetch next cc-step
    bar_lgkm();
#pragma unroll
    for (int ks = 0; ks < 2; ++ks) {
#pragma unroll
      for (int pt = 0; pt < 8; ++pt) {
        bf16x8 bf = *(const bf16x8*)(xT + (pt * 16 + m16) * LD + ks * 32 + quad * 8);
        pac[pt] = __builtin_amdgcn_mfma_f32_16x16x32_bf16(afr[ks], bf, pac[pt], 0, 0, 0);
      }
    }
  }

  // g-invariant halo addressing, hoisted: plane-relative offset or -1.
  int hoff[21];
#pragma unroll
  for (int it = 0; it < 21; ++it) {
    int idx = t + it * 256;
    int pl = idx / 336, rem = idx - pl * 336;
    int iy = rem / XROW, ix = rem - iy * XROW;   // ix 22,23: harmless pad
    int gy = h0 + iy - PADn, gx = w0 + ix - PADn;
    hoff[it] = ((unsigned)gy < (unsigned)Hn && (unsigned)gx < (unsigned)Wn)
                   ? pl * HWn + gy * Wn + gx : -1;
  }

  // phase-2 staging regs (all 256 threads; proven spill-free scale)
  float ph[21];
  f32x4 pA2[4];
  const int wrow = q * 16 + m16;            // A row for kgen (rows>=49 discarded)
  const int wclamp = (wrow < KKn ? wrow : 0);
  auto issue_g = [&](int g) {
    const float* wsrow = w_span + ((long)g * KKn + wclamp) * CRn;
#pragma unroll
    for (int h = 0; h < 4; ++h)
      pA2[h] = *(const f32x4*)(wsrow + (h >> 1) * 32 + quad * 8 + (h & 1) * 4);
    const float* xg = x + xbase + (long)g * CGn * HWn;
#pragma unroll
    for (int it = 0; it < 21; ++it)
      ph[it] = (hoff[it] >= 0) ? xg[hoff[it]] : 0.f;
  };

  issue_g(0);  // loads fly over epilogue + pre-loop barrier

  // epilogue: BN+ReLU -> rT[p][o] bf16 pairs
#pragma unroll
  for (int pt = 0; pt < 8; ++pt) {
    int pp = pt * 16 + m16;
    float v0 = fmaxf(fmaf(pac[pt][0], bsc[0], bsh[0]), 0.f);
    float v1 = fmaxf(fmaf(pac[pt][1], bsc[1], bsh[1]), 0.f);
    float v2 = fmaxf(fmaf(pac[pt][2], bsc[2], bsh[2]), 0.f);
    float v3 = fmaxf(fmaf(pac[pt][3], bsc[3], bsh[3]), 0.f);
    ((unsigned*)s_rT)[pp * LDW + q * 8 + quad * 2 + 0] = packbf2(v0, v1);
    ((unsigned*)s_rT)[pp * LDW + q * 8 + quad * 2 + 1] = packbf2(v2, v3);
  }

  // ---------------- Phase 2: 2 barriers per group ----------------
  float* s_w = s_u;                          // [49 k][132] fp32
  const int cgA = q + 4 * s;                 // this lane's 2 cg planes
  const int cgB = cgA + 8;
  const float* plA = s_xh + cgA * XPS;
  const float* plB = s_xh + cgB * XPS;
  const long opix = (h0 + py) * Wn + (w0 + px0);

  bar_lgkm();  // s_rT visible to all; xT(s_u) reads drained before s_w writes

  for (int g = 0; g < Gn; ++g) {
    // ---- P0: halo writes + kernel-gen (A-frag from regs) -> s_w ----
#pragma unroll
    for (int it = 0; it < 21; ++it)          // linear: LDS offset == idx
      s_xh[t + it * 256] = ph[it];

    bf16x8 afr2[2];
#pragma unroll
    for (int ks = 0; ks < 2; ++ks) {
      unsigned* ap = (unsigned*)&afr2[ks];
      f32x4 lo = pA2[ks * 2], hi = pA2[ks * 2 + 1];
      ap[0] = packbf2(lo[0], lo[1]); ap[1] = packbf2(lo[2], lo[3]);
      ap[2] = packbf2(hi[0], hi[1]); ap[3] = packbf2(hi[2], hi[3]);
    }

    f32x4 wac[8];
#pragma unroll
    for (int pt = 0; pt < 8; ++pt) wac[pt] = (f32x4){0.f, 0.f, 0.f, 0.f};
#pragma unroll
    for (int ks = 0; ks < 2; ++ks) {
#pragma unroll
      for (int pt = 0; pt < 8; ++pt) {
        bf16x8 bf = *(const bf16x8*)(s_rT + (pt * 16 + m16) * LD + ks * 32 + quad * 8);
        wac[pt] = __builtin_amdgcn_mfma_f32_16x16x32_bf16(afr2[ks], bf, wac[pt], 0, 0, 0);
      }
    }
    {
      int kb = q * 16 + quad * 4;
#pragma unroll
      for (int r = 0; r < 4; ++r) {
        if (kb + r < KKn) {
#pragma unroll
          for (int pt = 0; pt < 8; ++pt)
            s_w[(kb + r) * WLD + pt * 16 + m16] = wac[pt][r];
        }
      }
    }
    bar_lgkm();

    // ---- P1: prefetch g+1 (flies over barriers) + involution ----
    if (g + 1 < Gn) issue_g(g + 1);

    f32x4 a0 = (f32x4){0.f, 0.f, 0.f, 0.f};
    f32x4 a1 = (f32x4){0.f, 0.f, 0.f, 0.f};
#pragma unroll 1
    for (int i = 0; i < Kn; ++i) {
      f32x4 wr_[7];
#pragma unroll
      for (int jx = 0; jx < Kn; ++jx)
        wr_[jx] = *(const f32x4*)(s_w + (i * Kn + jx) * WLD + py * 16 + px0);
      const float* rA = plA + (py + i) * XROW + px0;
      const float* rB = plB + (py + i) * XROW + px0;
      f32x4 xa0 = *(const f32x4*)rA, xa1 = *(const f32x4*)(rA + 4), xa2 = *(const f32x4*)(rA + 8);
      f32x4 xb0 = *(const f32x4*)rB, xb1 = *(const f32x4*)(rB + 4), xb2 = *(const f32x4*)(rB + 8);
      float xa[12] = {xa0[0], xa0[1], xa0[2], xa0[3], xa1[0], xa1[1], xa1[2], xa1[3],
                      xa2[0], xa2[1], xa2[2], xa2[3]};
      float xb[12] = {xb0[0], xb0[1], xb0[2], xb0[3], xb1[0], xb1[1], xb1[2], xb1[3],
                      xb2[0], xb2[1], xb2[2], xb2[3]};
#pragma unroll
      for (int jx = 0; jx < Kn; ++jx) {
#pragma unroll
        for (int j = 0; j < 4; ++j) {
          a0[j] = fmaf(wr_[jx][j], xa[jx + j], a0[j]);
          a1[j] = fmaf(wr_[jx][j], xb[jx + j], a1[j]);
        }
      }
    }
    float* ob = out + xbase + (long)(g * CGn) * HWn + opix;
    *(f32x4*)(ob + (long)cgA * HWn) = a0;
    *(f32x4*)(ob + (long)cgB * HWn) = a1;

    bar_lgkm();  // invol reads of s_w/s_xh drained before next P0 overwrites
  }
}

extern "C" void kernel_launch(void* const* d_in, const int* in_sizes, int n_in,
                              void* d_out, int out_size, void* d_ws, size_t ws_size,
                              hipStream_t stream) {
  const float* x        = (const float*)d_in[0];
  const float* w_reduce = (const float*)d_in[1];
  const float* w_span   = (const float*)d_in[2];
  const float* bn_gamma = (const float*)d_in[3];
  const float* bn_beta  = (const float*)d_in[4];
  const float* bn_mean  = (const float*)d_in[5];
  const float* bn_var   = (const float*)d_in[6];
  float* outp = (float*)d_out;

  dim3 grid(512, 1, 1);  // 1-D for XCD-aware swizzle; 2 blocks/CU
  invol_fused<<<grid, 256, 0, stream>>>(x, w_reduce, w_span, bn_gamma,
                                        bn_beta, bn_mean, bn_var, outp);
}